// Round 1
// baseline (121.124 us; speedup 1.0000x reference)
//
#include <hip/hip_runtime.h>

// Problem constants (reference shape (64,1,480,640) fp32)
#define B_SAMPLES 64
#define NPS       307200      // elements per sample = 480*640
#define F4PS      76800       // float4 per sample
#define BPS       30          // blocks per sample
#define F4PB      2560        // float4 per block  (F4PS/BPS)
#define TPB       256         // threads per block (F4PB/TPB = 10 iters)
#define EPS_DET   1e-6

__device__ __forceinline__ bool finitef(float x) {
    return (__float_as_uint(x) & 0x7f800000u) != 0x7f800000u;
}

// ---------------------------------------------------------------------------
// Kernel 0: detect mask layout. int32 0/1 => bytes at 4k+{1,2,3} are all zero.
// byte-bool => ~half those bytes are 1. flag=1 -> byte layout, 0 -> int32.
// ---------------------------------------------------------------------------
__global__ void detect_mask_layout(const unsigned char* __restrict__ mask,
                                   int* __restrict__ flag) {
    unsigned v = 0;
    for (int j = threadIdx.x; j < 65536; j += TPB) {
        v |= mask[4 * j + 1];
        v |= mask[4 * j + 2];
        v |= mask[4 * j + 3];
    }
    if (v) atomicOr(flag, 1);
}

// ---------------------------------------------------------------------------
// Block reduce 5 doubles -> partials[blockIdx.x*5 + q]
// ---------------------------------------------------------------------------
__device__ __forceinline__ void block_reduce5(double v0, double v1, double v2,
                                              double v3, double v4,
                                              double* __restrict__ out5) {
    __shared__ double red[4][5];
    const int lane = threadIdx.x & 63;
    const int w = threadIdx.x >> 6;
    double vals[5] = {v0, v1, v2, v3, v4};
#pragma unroll
    for (int q = 0; q < 5; ++q) {
        double v = vals[q];
#pragma unroll
        for (int off = 32; off; off >>= 1) v += __shfl_down(v, off);
        if (lane == 0) red[w][q] = v;
    }
    __syncthreads();
    if (threadIdx.x == 0) {
#pragma unroll
        for (int q = 0; q < 5; ++q)
            out5[q] = red[0][q] + red[1][q] + red[2][q] + red[3][q];
    }
}

// ---------------------------------------------------------------------------
// Kernel 1: per-block masked partial sums {n, sum_p, sum_t, sum_p2, sum_pt}
// ---------------------------------------------------------------------------
__global__ void __launch_bounds__(TPB)
sums_kernel(const float* __restrict__ pred, const float* __restrict__ target,
            const void* __restrict__ mask, const int* __restrict__ flag,
            double* __restrict__ partials) {
    const int s = blockIdx.x / BPS;
    const int blk = blockIdx.x % BPS;
    const int base4 = s * F4PS + blk * F4PB;
    const bool byteLayout = (*flag != 0);

    const float4* p4 = (const float4*)pred;
    const float4* t4 = (const float4*)target;

    float n = 0.f, sp = 0.f, st = 0.f, sp2 = 0.f, spt = 0.f;

    auto accum = [&](float p, float t, bool mv) {
        bool ok = mv && finitef(p) && finitef(t);
        float pv = ok ? p : 0.f;
        float tv = ok ? t : 0.f;
        n += ok ? 1.f : 0.f;
        sp += pv;
        st += tv;
        sp2 += pv * pv;
        spt += pv * tv;
    };

    if (byteLayout) {
        const unsigned* m4 = (const unsigned*)mask;  // 4 bool bytes per load
#pragma unroll
        for (int k = 0; k < F4PB / TPB; ++k) {
            const int i4 = base4 + k * TPB + threadIdx.x;
            float4 p = p4[i4];
            float4 t = t4[i4];
            unsigned mm = m4[i4];
            accum(p.x, t.x, (mm & 0x000000ffu) != 0);
            accum(p.y, t.y, (mm & 0x0000ff00u) != 0);
            accum(p.z, t.z, (mm & 0x00ff0000u) != 0);
            accum(p.w, t.w, (mm & 0xff000000u) != 0);
        }
    } else {
        const int4* m4 = (const int4*)mask;
#pragma unroll
        for (int k = 0; k < F4PB / TPB; ++k) {
            const int i4 = base4 + k * TPB + threadIdx.x;
            float4 p = p4[i4];
            float4 t = t4[i4];
            int4 mm = m4[i4];
            accum(p.x, t.x, mm.x != 0);
            accum(p.y, t.y, mm.y != 0);
            accum(p.z, t.z, mm.z != 0);
            accum(p.w, t.w, mm.w != 0);
        }
    }

    block_reduce5((double)n, (double)sp, (double)st, (double)sp2, (double)spt,
                  partials + (size_t)blockIdx.x * 5);
}

// ---------------------------------------------------------------------------
// Kernel 2: per-sample solve for (a, b). 64 threads, one per sample.
// ---------------------------------------------------------------------------
__global__ void solve_kernel(const double* __restrict__ partials,
                             double* __restrict__ params) {
    const int s = threadIdx.x;
    double n = 0, sp = 0, st = 0, sp2 = 0, spt = 0;
    for (int b = 0; b < BPS; ++b) {
        const double* q = partials + (size_t)(s * BPS + b) * 5;
        n += q[0];
        sp += q[1];
        st += q[2];
        sp2 += q[3];
        spt += q[4];
    }
    double det = n * sp2 - sp * sp;
    bool safe = fabs(det) > EPS_DET;
    double a = safe ? (n * spt - sp * st) / det : 1.0;
    double bb = safe ? (st - a * sp) / fmax(n, 1.0) : 0.0;
    params[s * 3 + 0] = n;
    params[s * 3 + 1] = a;
    params[s * 3 + 2] = bb;
}

// ---------------------------------------------------------------------------
// Kernel 3: per-block masked residual partial sums |a*p + b - t|
// ---------------------------------------------------------------------------
__global__ void __launch_bounds__(TPB)
resid_kernel(const float* __restrict__ pred, const float* __restrict__ target,
             const void* __restrict__ mask, const int* __restrict__ flag,
             const double* __restrict__ params, double* __restrict__ rpart) {
    const int s = blockIdx.x / BPS;
    const int blk = blockIdx.x % BPS;
    const int base4 = s * F4PS + blk * F4PB;
    const bool byteLayout = (*flag != 0);
    const float av = (float)params[s * 3 + 1];
    const float bv = (float)params[s * 3 + 2];

    const float4* p4 = (const float4*)pred;
    const float4* t4 = (const float4*)target;

    float r = 0.f;
    auto accum = [&](float p, float t, bool mv) {
        bool ok = mv && finitef(p) && finitef(t);
        r += ok ? fabsf(av * p + bv - t) : 0.f;
    };

    if (byteLayout) {
        const unsigned* m4 = (const unsigned*)mask;
#pragma unroll
        for (int k = 0; k < F4PB / TPB; ++k) {
            const int i4 = base4 + k * TPB + threadIdx.x;
            float4 p = p4[i4];
            float4 t = t4[i4];
            unsigned mm = m4[i4];
            accum(p.x, t.x, (mm & 0x000000ffu) != 0);
            accum(p.y, t.y, (mm & 0x0000ff00u) != 0);
            accum(p.z, t.z, (mm & 0x00ff0000u) != 0);
            accum(p.w, t.w, (mm & 0xff000000u) != 0);
        }
    } else {
        const int4* m4 = (const int4*)mask;
#pragma unroll
        for (int k = 0; k < F4PB / TPB; ++k) {
            const int i4 = base4 + k * TPB + threadIdx.x;
            float4 p = p4[i4];
            float4 t = t4[i4];
            int4 mm = m4[i4];
            accum(p.x, t.x, mm.x != 0);
            accum(p.y, t.y, mm.y != 0);
            accum(p.z, t.z, mm.z != 0);
            accum(p.w, t.w, mm.w != 0);
        }
    }

    // block reduce single double
    __shared__ double red[4];
    const int lane = threadIdx.x & 63;
    const int w = threadIdx.x >> 6;
    double v = (double)r;
#pragma unroll
    for (int off = 32; off; off >>= 1) v += __shfl_down(v, off);
    if (lane == 0) red[w] = v;
    __syncthreads();
    if (threadIdx.x == 0)
        rpart[blockIdx.x] = red[0] + red[1] + red[2] + red[3];
}

// ---------------------------------------------------------------------------
// Kernel 4: final loss. One wave, thread s = sample s.
// ---------------------------------------------------------------------------
__global__ void final_kernel(const double* __restrict__ params,
                             const double* __restrict__ rpart,
                             float* __restrict__ out) {
    const int s = threadIdx.x;  // 64 threads = 1 wave
    double r = 0;
    for (int b = 0; b < BPS; ++b) r += rpart[s * BPS + b];
    const double n = params[s * 3 + 0];
    double per = r / fmax(n, 1.0);
    double inc = (n >= 2.0) ? 1.0 : 0.0;
    double v = per * inc;
#pragma unroll
    for (int off = 32; off; off >>= 1) {
        v += __shfl_down(v, off);
        inc += __shfl_down(inc, off);
    }
    if (s == 0) out[0] = (float)(inc > 0.0 ? v / fmax(inc, 1.0) : 0.0);
}

extern "C" void kernel_launch(void* const* d_in, const int* in_sizes, int n_in,
                              void* d_out, int out_size, void* d_ws, size_t ws_size,
                              hipStream_t stream) {
    const float* pred = (const float*)d_in[0];
    const float* target = (const float*)d_in[1];
    const void* mask = d_in[2];
    float* out = (float*)d_out;

    // workspace layout
    int* flag = (int*)d_ws;                               // [0, 4)
    double* partials = (double*)((char*)d_ws + 64);       // B*BPS*5 doubles
    double* params = partials + (size_t)B_SAMPLES * BPS * 5;  // B*3 doubles
    double* rpart = params + (size_t)B_SAMPLES * 3;       // B*BPS doubles

    // zero the detection flag only (everything else written unconditionally)
    hipMemsetAsync(d_ws, 0, 64, stream);

    detect_mask_layout<<<1, TPB, 0, stream>>>((const unsigned char*)mask, flag);
    sums_kernel<<<B_SAMPLES * BPS, TPB, 0, stream>>>(pred, target, mask, flag,
                                                     partials);
    solve_kernel<<<1, 64, 0, stream>>>(partials, params);
    resid_kernel<<<B_SAMPLES * BPS, TPB, 0, stream>>>(pred, target, mask, flag,
                                                      params, rpart);
    final_kernel<<<1, 64, 0, stream>>>(params, rpart, out);
}

// Round 2
// 86.198 us; speedup vs baseline: 1.4052x; 1.4052x over previous
//
#include <hip/hip_runtime.h>

// Problem constants (reference shape (64,1,480,640) fp32)
#define B_SAMPLES 64
#define NPS       307200      // elements per sample = 480*640
#define F4PS      76800       // float4 per sample
#define BPS       30          // blocks per sample
#define F4PB      2560        // float4 per block  (F4PS/BPS)
#define TPB       256         // threads per block
#define ITERS     10          // F4PB / TPB
#define EPS_DET   1e-6

__device__ __forceinline__ bool finitef(float x) {
    return (__float_as_uint(x) & 0x7f800000u) != 0x7f800000u;
}

// ---------------------------------------------------------------------------
// Kernel 0: detect mask layout. int32 0/1 => bytes at 4k+{1,2,3} all zero.
// byte-bool => ~half of them are 1. flag=1 -> byte layout, 0 -> int32.
// Scans first 256 KiB with dwordx4 loads. 16 blocks x 256 thr x 4 uint4.
// ---------------------------------------------------------------------------
__global__ void detect_mask_layout(const uint4* __restrict__ mask,
                                   int* __restrict__ flag) {
    unsigned v = 0;
    const int base = blockIdx.x * TPB + threadIdx.x;   // 4096 threads
#pragma unroll
    for (int k = 0; k < 4; ++k) {
        uint4 m = mask[base + k * 4096];               // 16384 uint4 = 256 KiB
        v |= (m.x | m.y | m.z | m.w) & 0xffffff00u;
    }
    if (v) atomicOr(flag, 1);
}

// ---------------------------------------------------------------------------
// Block reduce 5 doubles -> out5[q]
// ---------------------------------------------------------------------------
__device__ __forceinline__ void block_reduce5(double v0, double v1, double v2,
                                              double v3, double v4,
                                              double* __restrict__ out5) {
    __shared__ double red[4][5];
    const int lane = threadIdx.x & 63;
    const int w = threadIdx.x >> 6;
    double vals[5] = {v0, v1, v2, v3, v4};
#pragma unroll
    for (int q = 0; q < 5; ++q) {
        double v = vals[q];
#pragma unroll
        for (int off = 32; off; off >>= 1) v += __shfl_down(v, off);
        if (lane == 0) red[w][q] = v;
    }
    __syncthreads();
    if (threadIdx.x == 0) {
#pragma unroll
        for (int q = 0; q < 5; ++q)
            out5[q] = red[0][q] + red[1][q] + red[2][q] + red[3][q];
    }
}

// ---------------------------------------------------------------------------
// Kernel 1: per-block masked partial sums {n, sum_p, sum_t, sum_p2, sum_pt}
// Batched loads: issue all iterations' loads into register arrays first
// (single waitcnt), then consume. ~100 VGPR -> 4 waves/SIMD, 30 loads in
// flight per wave => BW-bound instead of latency-bound.
// ---------------------------------------------------------------------------
__global__ void __launch_bounds__(TPB, 4)
sums_kernel(const float* __restrict__ pred, const float* __restrict__ target,
            const void* __restrict__ mask, const int* __restrict__ flag,
            double* __restrict__ partials) {
    const int s = blockIdx.x / BPS;
    const int blk = blockIdx.x % BPS;
    const int base4 = s * F4PS + blk * F4PB + threadIdx.x;
    const bool byteLayout = (*flag != 0);

    const float4* p4 = (const float4*)pred;
    const float4* t4 = (const float4*)target;

    float n = 0.f, sp = 0.f, st = 0.f, sp2 = 0.f, spt = 0.f;

    auto accum = [&](float p, float t, bool mv) {
        bool ok = mv && finitef(p) && finitef(t);
        float pv = ok ? p : 0.f;
        float tv = ok ? t : 0.f;
        n += ok ? 1.f : 0.f;
        sp += pv;
        st += tv;
        sp2 += pv * pv;
        spt += pv * tv;
    };

    if (byteLayout) {
        const unsigned* m4 = (const unsigned*)mask;  // 4 bool bytes per load
        float4 pv[ITERS], tv[ITERS];
        unsigned mv[ITERS];
#pragma unroll
        for (int k = 0; k < ITERS; ++k) {
            const int i4 = base4 + k * TPB;
            pv[k] = p4[i4];
            tv[k] = t4[i4];
            mv[k] = m4[i4];
        }
#pragma unroll
        for (int k = 0; k < ITERS; ++k) {
            accum(pv[k].x, tv[k].x, (mv[k] & 0x000000ffu) != 0);
            accum(pv[k].y, tv[k].y, (mv[k] & 0x0000ff00u) != 0);
            accum(pv[k].z, tv[k].z, (mv[k] & 0x00ff0000u) != 0);
            accum(pv[k].w, tv[k].w, (mv[k] & 0xff000000u) != 0);
        }
    } else {
        const int4* m4 = (const int4*)mask;
#pragma unroll
        for (int half = 0; half < 2; ++half) {
            float4 pv[5], tv[5];
            int4 mv[5];
#pragma unroll
            for (int k = 0; k < 5; ++k) {
                const int i4 = base4 + (half * 5 + k) * TPB;
                pv[k] = p4[i4];
                tv[k] = t4[i4];
                mv[k] = m4[i4];
            }
#pragma unroll
            for (int k = 0; k < 5; ++k) {
                accum(pv[k].x, tv[k].x, mv[k].x != 0);
                accum(pv[k].y, tv[k].y, mv[k].y != 0);
                accum(pv[k].z, tv[k].z, mv[k].z != 0);
                accum(pv[k].w, tv[k].w, mv[k].w != 0);
            }
        }
    }

    block_reduce5((double)n, (double)sp, (double)st, (double)sp2, (double)spt,
                  partials + (size_t)blockIdx.x * 5);
}

// ---------------------------------------------------------------------------
// Kernel 2: per-sample solve for (a, b). 64 threads, one per sample.
// ---------------------------------------------------------------------------
__global__ void solve_kernel(const double* __restrict__ partials,
                             double* __restrict__ params) {
    const int s = threadIdx.x;
    double n = 0, sp = 0, st = 0, sp2 = 0, spt = 0;
    for (int b = 0; b < BPS; ++b) {
        const double* q = partials + (size_t)(s * BPS + b) * 5;
        n += q[0];
        sp += q[1];
        st += q[2];
        sp2 += q[3];
        spt += q[4];
    }
    double det = n * sp2 - sp * sp;
    bool safe = fabs(det) > EPS_DET;
    double a = safe ? (n * spt - sp * st) / det : 1.0;
    double bb = safe ? (st - a * sp) / fmax(n, 1.0) : 0.0;
    params[s * 3 + 0] = n;
    params[s * 3 + 1] = a;
    params[s * 3 + 2] = bb;
}

// ---------------------------------------------------------------------------
// Kernel 3: per-block masked residual partial sums |a*p + b - t|
// ---------------------------------------------------------------------------
__global__ void __launch_bounds__(TPB, 4)
resid_kernel(const float* __restrict__ pred, const float* __restrict__ target,
             const void* __restrict__ mask, const int* __restrict__ flag,
             const double* __restrict__ params, double* __restrict__ rpart) {
    const int s = blockIdx.x / BPS;
    const int blk = blockIdx.x % BPS;
    const int base4 = s * F4PS + blk * F4PB + threadIdx.x;
    const bool byteLayout = (*flag != 0);
    const float av = (float)params[s * 3 + 1];
    const float bv = (float)params[s * 3 + 2];

    const float4* p4 = (const float4*)pred;
    const float4* t4 = (const float4*)target;

    float r = 0.f;
    auto accum = [&](float p, float t, bool mv) {
        bool ok = mv && finitef(p) && finitef(t);
        r += ok ? fabsf(av * p + bv - t) : 0.f;
    };

    if (byteLayout) {
        const unsigned* m4 = (const unsigned*)mask;
        float4 pv[ITERS], tv[ITERS];
        unsigned mv[ITERS];
#pragma unroll
        for (int k = 0; k < ITERS; ++k) {
            const int i4 = base4 + k * TPB;
            pv[k] = p4[i4];
            tv[k] = t4[i4];
            mv[k] = m4[i4];
        }
#pragma unroll
        for (int k = 0; k < ITERS; ++k) {
            accum(pv[k].x, tv[k].x, (mv[k] & 0x000000ffu) != 0);
            accum(pv[k].y, tv[k].y, (mv[k] & 0x0000ff00u) != 0);
            accum(pv[k].z, tv[k].z, (mv[k] & 0x00ff0000u) != 0);
            accum(pv[k].w, tv[k].w, (mv[k] & 0xff000000u) != 0);
        }
    } else {
        const int4* m4 = (const int4*)mask;
#pragma unroll
        for (int half = 0; half < 2; ++half) {
            float4 pv[5], tv[5];
            int4 mv[5];
#pragma unroll
            for (int k = 0; k < 5; ++k) {
                const int i4 = base4 + (half * 5 + k) * TPB;
                pv[k] = p4[i4];
                tv[k] = t4[i4];
                mv[k] = m4[i4];
            }
#pragma unroll
            for (int k = 0; k < 5; ++k) {
                accum(pv[k].x, tv[k].x, mv[k].x != 0);
                accum(pv[k].y, tv[k].y, mv[k].y != 0);
                accum(pv[k].z, tv[k].z, mv[k].z != 0);
                accum(pv[k].w, tv[k].w, mv[k].w != 0);
            }
        }
    }

    // block reduce single double
    __shared__ double red[4];
    const int lane = threadIdx.x & 63;
    const int w = threadIdx.x >> 6;
    double v = (double)r;
#pragma unroll
    for (int off = 32; off; off >>= 1) v += __shfl_down(v, off);
    if (lane == 0) red[w] = v;
    __syncthreads();
    if (threadIdx.x == 0)
        rpart[blockIdx.x] = red[0] + red[1] + red[2] + red[3];
}

// ---------------------------------------------------------------------------
// Kernel 4: final loss. One wave, thread s = sample s.
// ---------------------------------------------------------------------------
__global__ void final_kernel(const double* __restrict__ params,
                             const double* __restrict__ rpart,
                             float* __restrict__ out) {
    const int s = threadIdx.x;  // 64 threads = 1 wave
    double r = 0;
    for (int b = 0; b < BPS; ++b) r += rpart[s * BPS + b];
    const double n = params[s * 3 + 0];
    double per = r / fmax(n, 1.0);
    double inc = (n >= 2.0) ? 1.0 : 0.0;
    double v = per * inc;
#pragma unroll
    for (int off = 32; off; off >>= 1) {
        v += __shfl_down(v, off);
        inc += __shfl_down(inc, off);
    }
    if (s == 0) out[0] = (float)(inc > 0.0 ? v / fmax(inc, 1.0) : 0.0);
}

extern "C" void kernel_launch(void* const* d_in, const int* in_sizes, int n_in,
                              void* d_out, int out_size, void* d_ws, size_t ws_size,
                              hipStream_t stream) {
    const float* pred = (const float*)d_in[0];
    const float* target = (const float*)d_in[1];
    const void* mask = d_in[2];
    float* out = (float*)d_out;

    // workspace layout
    int* flag = (int*)d_ws;                                   // [0, 4)
    double* partials = (double*)((char*)d_ws + 64);           // B*BPS*5 doubles
    double* params = partials + (size_t)B_SAMPLES * BPS * 5;  // B*3 doubles
    double* rpart = params + (size_t)B_SAMPLES * 3;           // B*BPS doubles

    // zero the detection flag only (everything else written unconditionally)
    hipMemsetAsync(d_ws, 0, 64, stream);

    detect_mask_layout<<<16, TPB, 0, stream>>>((const uint4*)mask, flag);
    sums_kernel<<<B_SAMPLES * BPS, TPB, 0, stream>>>(pred, target, mask, flag,
                                                     partials);
    solve_kernel<<<1, 64, 0, stream>>>(partials, params);
    resid_kernel<<<B_SAMPLES * BPS, TPB, 0, stream>>>(pred, target, mask, flag,
                                                      params, rpart);
    final_kernel<<<1, 64, 0, stream>>>(params, rpart, out);
}